// Round 7
// baseline (150.643 us; speedup 1.0000x reference)
//
#include <hip/hip_runtime.h>
#include <math.h>

typedef __attribute__((ext_vector_type(8))) short short8;
typedef __attribute__((ext_vector_type(4))) float f32x4;
typedef __attribute__((ext_vector_type(16))) float f32x16;

#define NTAP 125
#define DCH 32

static __device__ __forceinline__ unsigned short f2bf(float f) {
    union { float f; unsigned u; } v; v.f = f;
    unsigned u = v.u;
    return (unsigned short)((u + 0x7FFFu + ((u >> 16) & 1u)) >> 16);
}

static __device__ __forceinline__ void gld_lds16(const void* g, void* l) {
    __builtin_amdgcn_global_load_lds(
        (const __attribute__((address_space(1))) unsigned int*)g,
        (__attribute__((address_space(3))) unsigned int*)l, 16, 0, 0);
}

// ---------------------------------------------------------------------------
// Kernel 1 (fused build+pack): build conv weights for tap t in LDS, then
// pack to bf16 B-fragments kwb[tap][kh][lane][8] for mfma_f32_32x32x16_bf16.
// Skip connection folded into center tap 62. (math verified R0-R6)
// ---------------------------------------------------------------------------
__global__ __launch_bounds__(128) void build_pack(
    const float* __restrict__ weight,
    const float* __restrict__ w_sc0,
    const float* __restrict__ w_sc1,
    unsigned short* __restrict__ kwb)
{
    const int t = blockIdx.x;
    const int dx = t / 25, dy = (t / 5) % 5, dz = t % 5;
    const float px = dx - 2.0f, py = dy - 2.0f, pz = dz - 2.0f;
    const float d = sqrtf(px * px + py * py + pz * pz);

    const float stepv = 2.5f / 6.0f;
    const float embc = 1.14136f * expf(2.0f);
    float emb[5];
#pragma unroll
    for (int n = 0; n < 5; ++n) {
        float diff = (d - stepv * (float)(n + 1)) / stepv;
        float a = diff + 1.0f, bb = 1.0f - diff;
        float v = 0.0f;
        if (a > 0.0f && bb > 0.0f)
            v = embc * expf(-1.0f / a) * expf(-1.0f / bb);
        emb[n] = v;
    }

    const float inv_d = (d > 0.0f) ? 1.0f / d : 0.0f;
    const float ux = px * inv_d, uy = py * inv_d, uz = pz * inv_d;
    const float s3 = 1.73205081f, s5 = 2.23606798f, s15 = 3.87298335f;
    float sh[9];
    sh[0] = 1.0f;
    sh[1] = s3 * ux; sh[2] = s3 * uy; sh[3] = s3 * uz;
    sh[4] = s15 * ux * uz;
    sh[5] = s15 * ux * uy;
    sh[6] = s5 * (uy * uy - 0.5f * (ux * ux + uz * uz));
    sh[7] = s15 * uy * uz;
    sh[8] = 0.5f * s15 * (uz * uz - ux * ux);

    const float i_s2 = 0.70710678f, i_s6 = 0.40824829f, i_s5 = 0.44721360f;
    float T[3][3];
    T[0][0] = i_s5 * (-sh[6] * i_s6 - sh[8] * i_s2);
    T[0][1] = i_s5 * (sh[5] * i_s2);
    T[0][2] = i_s5 * (sh[4] * i_s2);
    T[1][0] = T[0][1];
    T[1][1] = i_s5 * (2.0f * sh[6] * i_s6);
    T[1][2] = i_s5 * (sh[7] * i_s2);
    T[2][0] = T[0][2];
    T[2][1] = T[1][2];
    T[2][2] = i_s5 * (-sh[6] * i_s6 + sh[8] * i_s2);

    __shared__ float Wt[320];
    __shared__ float kws[1024];              // [ci=32][co=32] for this tap
    for (int col = threadIdx.x; col < 320; col += 128) {
        float a = 0.0f;
#pragma unroll
        for (int n = 0; n < 5; ++n) a += emb[n] * weight[n * 320 + col];
        Wt[col] = a * (1.0f / 125.0f);
    }
    __syncthreads();

    const float pw0 = 0.25f;
    const float pw1 = 0.35355339f;
    const float inv_s3 = 0.57735027f;
    const float inv_s8 = 0.35355339f;

    for (int idx = threadIdx.x; idx < 1024; idx += 128) {
        const int o = idx >> 5, i = idx & 31;
        float val;
        if (o < 8) {
            if (i < 8) {
                val = pw0 * Wt[i * 8 + o];
            } else {
                const int u = (i - 8) / 3, m = (i - 8) % 3;
                val = pw0 * inv_s3 * Wt[192 + u * 8 + o] * sh[1 + m];
            }
        } else {
            const int v = (o - 8) / 3, k = (o - 8) % 3;
            if (i < 8) {
                val = pw1 * inv_s3 * Wt[64 + i * 8 + v] * sh[1 + k];
            } else {
                const int u = (i - 8) / 3, m = (i - 8) % 3;
                float tv = Wt[256 + u * 8 + v] * T[m][k];
                if (m == k) tv += inv_s3 * Wt[128 + u * 8 + v];
                val = pw1 * tv;
            }
        }
        if (t == 62) {
            if (o < 8 && i < 8) {
                val += inv_s8 * w_sc0[i * 8 + o];
            } else if (o >= 8 && i >= 8) {
                const int u = (i - 8) / 3, m = (i - 8) % 3;
                const int v = (o - 8) / 3, k = (o - 8) % 3;
                if (m == k) val += inv_s8 * w_sc1[u * 8 + v];
            }
        }
        kws[i * 32 + o] = val;
    }
    __syncthreads();

    // pack: kwb[tap][kh][lane][8], ci = kh*16 + (l>>5)*8 + j, co = l&31
    const int tid = threadIdx.x;
    const int kh = tid >> 6, l = tid & 63;
    const int co = l & 31;
    const int cib = kh * 16 + (l >> 5) * 8;
    unsigned short v[8];
#pragma unroll
    for (int j = 0; j < 8; ++j)
        v[j] = f2bf(kws[(cib + j) * 32 + co]);
    uint4 o;
    o.x = (unsigned)v[0] | ((unsigned)v[1] << 16);
    o.y = (unsigned)v[2] | ((unsigned)v[3] << 16);
    o.z = (unsigned)v[4] | ((unsigned)v[5] << 16);
    o.w = (unsigned)v[6] | ((unsigned)v[7] << 16);
    *reinterpret_cast<uint4*>(kwb + ((size_t)(t * 2 + kh) * 64 + l) * 8) = o;
}

// ---------------------------------------------------------------------------
// Kernel 2: transpose x fp32 [b][ci][X][Y][Z] -> bf16 x_t[b][X][Y][Z][ci=32]
// ---------------------------------------------------------------------------
__global__ __launch_bounds__(256) void xpose(
    const float* __restrict__ x, unsigned short* __restrict__ xt)
{
    const int xx = blockIdx.x, yy = blockIdx.y, b = blockIdx.z;
    const int t = threadIdx.x;
    const int z = t & 63, part = t >> 6;
    const float* src = x + ((((size_t)b * 32) * 64 + xx) * 64 + yy) * 64 + z;
    unsigned short v[8];
#pragma unroll
    for (int j = 0; j < 8; ++j)
        v[j] = f2bf(src[(size_t)(part * 8 + j) * 262144]);
    uint4 o;
    o.x = (unsigned)v[0] | ((unsigned)v[1] << 16);
    o.y = (unsigned)v[2] | ((unsigned)v[3] << 16);
    o.z = (unsigned)v[4] | ((unsigned)v[5] << 16);
    o.w = (unsigned)v[6] | ((unsigned)v[7] << 16);
    *reinterpret_cast<uint4*>(
        xt + ((((size_t)b * 64 + xx) * 64 + yy) * 64 + z) * 32 + part * 8) = o;
}

__global__ void zero_fill(float4* p) {
    p[threadIdx.x] = make_float4(0.f, 0.f, 0.f, 0.f);
}

// ---------------------------------------------------------------------------
// Kernel 3: implicit-GEMM conv via mfma_f32_32x32x16_bf16.
// R7 = R6 skeleton (tbuf slab, counted end-of-step vmcnt(5|4), raw
// s_barrier; PASSING) + compute-phase ds_reads as INLINE ASM:
// R1/R3/R6 were performance-identical (~7600 cyc/step, 44-46% MfmaUtil)
// under three different sync schedules -> the executed stream was the
// same: the waitcnt legalizer inserts s_waitcnt vmcnt(0) before the first
// C-level ds_read of each step (can't prove no alias with the outstanding
// global_load_lds DMA into the same LDS block), which serializes
// stage->compute in ALL variants and makes hand-placed counted vmcnts
// dead code. Fix: asm ds_read_b128 (invisible to that pass), one read per
// asm with "=&v" early-clobber (R4's dual-read asm without early-clobber
// let the first read's async return clobber the shared address reg ->
// absmax 6.39), 2-deep group pipeline with counted lgkmcnt(S) (S compile-
// time per xl) and sched_barrier(0) after every wait (rule #18). LDS base
// via __builtin_amdgcn_groupstaticsize() (=0, pure dynamic LDS).
// Block 512 thr (8 waves), tile 4x*8y*64z, grid 16*8*2 = 256 = 1 block/CU.
// LDS 155648 B: Bs[25][2][64][16B] (51200) + slab tbuf 3 x 34816.
// ---------------------------------------------------------------------------
__global__ __launch_bounds__(512, 2) void conv_mfma(
    const unsigned short* __restrict__ xt,   // [b][64][64][64][32] bf16
    const unsigned short* __restrict__ kwb,  // [125][2][64][8]
    const unsigned short* __restrict__ zpage,
    float* __restrict__ out)                 // [b][32][64][64][64]
{
    extern __shared__ unsigned short smem[];
    char* lds = (char*)smem;
    // dynamic LDS begins right after static LDS (none here) -> offset 0
    const unsigned lds0 = (unsigned)__builtin_amdgcn_groupstaticsize();

    const int tid = threadIdx.x;
    const int lane = tid & 63;
    const int wv = tid >> 6;                 // 0..7
    const int oyp = wv >> 1, zh = wv & 1;    // oy pair 0..3, z half
    const int x0 = blockIdx.x * 4, y0 = blockIdx.y * 8;
    const int b = blockIdx.z;
    const int l31 = lane & 31, hi = lane >> 5;

    // A-read LDS byte addr (buf0, oyi=0); oyi=1: +4352 (asm offset imm);
    // buffers: + runtime rd in {0,34816,69632} (one v_add per group).
    int abase[5][2];
#pragma unroll
    for (int dz = 0; dz < 5; ++dz) {
        const int s = zh * 32 + l31 + dz;
#pragma unroll
        for (int kh = 0; kh < 2; ++kh) {
            const int cph = (kh * 2 + hi) ^ ((s >> 1) & 3);
            abase[dz][kh] = (int)lds0 +
                51200 + ((((oyp * 2 * 68 + s) << 2) | cph) << 4);
        }
    }
    const unsigned baddr = lds0 + (unsigned)(lane * 16);  // Bs at offset 0

    // slab staging precompute: 2176 chunks, c = tid + p*512
    // (p<4 all threads; p==4 only waves 0-1)
    int srow[5]; int soff[5]; bool szok[5];
#pragma unroll
    for (int p = 0; p < 5; ++p) {
        const int c = tid + p * 512;
        const int row = c / 272;
        const int rem = c - row * 272;
        const int slot = rem >> 2;
        const int clog = (rem & 3) ^ ((slot >> 1) & 3);
        const int z = slot - 2;
        srow[p] = row;
        szok[p] = ((unsigned)z < 64u);
        soff[p] = row * 2048 + z * 32 + clog * 8;
    }

    // Bs staging precompute: 3200 chunks, c = tid + k*512
    int bsrc[7];
#pragma unroll
    for (int k = 0; k < 7; ++k) {
        const int c = tid + k * 512;
        const int tp = c >> 7, rem = c & 127;
        const int dxx = tp / 5, dzz = tp - dxx * 5;
        bsrc[k] = (dxx * 25 + dzz) * 128 + rem;
    }

    auto issue_bs = [&](int dy) {
#pragma unroll
        for (int k = 0; k < 7; ++k) {
            const int c0 = wv * 64 + k * 512;   // wave-uniform dest base
            if (c0 < 3200) {
                gld_lds16(kwb + ((size_t)(bsrc[k] + dy * 640)) * 8,
                          lds + c0 * 16);
            }
        }
    };

    auto issue_slab = [&](int dyn, int xln, int dstoff) {
        const int yyb = y0 + dyn - 2;
        const int xx = x0 + xln - 2;
        const bool xok = ((unsigned)xx < 64u);
        const long long xyb =
            (long long)(b * 64 + xx) * 131072 + (long long)yyb * 2048;
        char* dst = lds + 51200 + dstoff;    // dstoff uniform
#pragma unroll
        for (int p = 0; p < 4; ++p) {
            const int yy = yyb + srow[p];
            const bool ok = xok && ((unsigned)yy < 64u) && szok[p];
            const unsigned short* src = ok ? (xt + xyb + soff[p]) : zpage;
            gld_lds16(src, dst + (wv * 64 + p * 512) * 16);
        }
        if (wv < 2) {   // chunks 2048..2175
            const int yy = yyb + srow[4];
            const bool ok = xok && ((unsigned)yy < 64u) && szok[4];
            const unsigned short* src = ok ? (xt + xyb + soff[4]) : zpage;
            gld_lds16(src, dst + (wv * 64 + 2048) * 16);
        }
    };

    // counted wait: retire everything older than my newest slab issue
    auto wait_keep_slab = [&]() {
        if (wv < 2) asm volatile("s_waitcnt vmcnt(5)" ::: "memory");
        else        asm volatile("s_waitcnt vmcnt(4)" ::: "memory");
    };

    f32x16 acc[2][4];
#pragma unroll
    for (int oyi = 0; oyi < 2; ++oyi)
#pragma unroll
        for (int ox = 0; ox < 4; ++ox)
#pragma unroll
            for (int e = 0; e < 16; ++e) acc[oyi][ox][e] = 0.0f;

    // prologue: Bs(0), slab(0)->buf0, slab(1)->buf1; retire Bs+slab(0),
    // keep slab(1) in flight.
    issue_bs(0);
    __builtin_amdgcn_sched_barrier(0);
    issue_slab(0, 0, 0);
    __builtin_amdgcn_sched_barrier(0);
    issue_slab(0, 1, 34816);
    __builtin_amdgcn_sched_barrier(0);
    wait_keep_slab();
    __builtin_amdgcn_s_barrier();

    int rd = 0;            // buffer being computed this step
    int prev = 69632;      // buffer read last step = stage target for t+2

    for (int dy = 0; dy < 5; ++dy) {
#pragma unroll
        for (int xl = 0; xl < 8; ++xl) {
            const bool bdry = (xl == 0) && (dy > 0);
            if (bdry) {
                // Bs(dy): all readers of Bs(dy-1) passed last barrier
                issue_bs(dy);
                __builtin_amdgcn_sched_barrier(0);
            }
            // stage slab(t+2) into the buffer read at t-1
            if (!(dy == 4 && xl >= 6)) {
                const int ndy = (xl >= 6) ? dy + 1 : dy;
                const int nxl = (xl >= 6) ? xl - 6 : xl + 2;
                issue_slab(ndy, nxl, prev);
                __builtin_amdgcn_sched_barrier(0);
            }
            if (bdry) {
                // retire slab(t+1)+Bs(dy), keep slab(t+2) in flight
                wait_keep_slab();
                __builtin_amdgcn_s_barrier();
            }

            // ---- compute from buf at rd: inline-asm ds_read pipeline ----
            const int oxlo = (xl - 4 > 0) ? (xl - 4) : 0;
            const int oxhi = (xl < 3) ? xl : 3;
            const int S = 2 + (oxhi - oxlo + 1);     // reads per group

            short8 A0[2], A1[2], B[2][4];

            // issue group 0 (dz=0, kh=0)
            {
                const unsigned aa = (unsigned)(abase[0][0] + rd);
                asm volatile("ds_read_b128 %0, %1"
                             : "=&v"(A0[0]) : "v"(aa));
                asm volatile("ds_read_b128 %0, %1 offset:4352"
                             : "=&v"(A1[0]) : "v"(aa));
#pragma unroll
                for (int ox = 0; ox < 4; ++ox) {
                    if (ox < oxlo || ox > oxhi) continue;
                    const unsigned bb = baddr +
                        (unsigned)((((xl - ox) * 5 + 0) * 2 + 0) << 10);
                    asm volatile("ds_read_b128 %0, %1"
                                 : "=&v"(B[0][ox]) : "v"(bb));
                }
            }
#pragma unroll
            for (int g = 0; g < 10; ++g) {
                const int cs = g & 1;
                if (g < 9) {
                    const int g1 = g + 1;
                    const int dz1 = g1 >> 1, kh1 = g1 & 1, ns = g1 & 1;
                    const unsigned aa = (unsigned)(abase[dz1][kh1] + rd);
                    asm volatile("ds_read_b128 %0, %1"
                                 : "=&v"(A0[ns]) : "v"(aa));
                    asm volatile("ds_read_b128 %0, %1 offset:4352"
                                 : "=&v"(A1[ns]) : "v"(aa));
#pragma unroll
                    for (int ox = 0; ox < 4; ++ox) {
                        if (ox < oxlo || ox > oxhi) continue;
                        const unsigned bb = baddr +
                            (unsigned)((((xl - ox) * 5 + dz1) * 2 + kh1)
                                       << 10);
                        asm volatile("ds_read_b128 %0, %1"
                                     : "=&v"(B[ns][ox]) : "v"(bb));
                    }
                    // wait until only group g+1's S reads are outstanding
                    if (S == 3)
                        asm volatile("s_waitcnt lgkmcnt(3)" ::: "memory");
                    else if (S == 4)
                        asm volatile("s_waitcnt lgkmcnt(4)" ::: "memory");
                    else if (S == 5)
                        asm volatile("s_waitcnt lgkmcnt(5)" ::: "memory");
                    else
                        asm volatile("s_waitcnt lgkmcnt(6)" ::: "memory");
                } else {
                    asm volatile("s_waitcnt lgkmcnt(0)" ::: "memory");
                }
                __builtin_amdgcn_sched_barrier(0);   // rule #18
#pragma unroll
                for (int ox = 0; ox < 4; ++ox) {
                    if (ox < oxlo || ox > oxhi) continue;
                    acc[0][ox] = __builtin_amdgcn_mfma_f32_32x32x16_bf16(
                        A0[cs], B[cs][ox], acc[0][ox], 0, 0, 0);
                    acc[1][ox] = __builtin_amdgcn_mfma_f32_32x32x16_bf16(
                        A1[cs], B[cs][ox], acc[1][ox], 0, 0, 0);
                }
            }

            // end of step: retire slab(t+1), keep slab(t+2) in flight
            if (dy == 4 && xl >= 6) {
                asm volatile("s_waitcnt vmcnt(0)" ::: "memory");
            } else {
                wait_keep_slab();
            }
            if (!(dy == 4 && xl == 7))
                __builtin_amdgcn_s_barrier();

            // rotate buffers
            const int tmp = rd;
            rd = (rd == 69632) ? 0 : rd + 34816;
            prev = tmp;
        }
    }

    // epilogue: D lane l: co = l&31, z = zh*32 + rq*8 + (l>>5)*4 + (r&3)
#pragma unroll
    for (int oyi = 0; oyi < 2; ++oyi) {
        const int yy = y0 + oyp * 2 + oyi;
#pragma unroll
        for (int ox = 0; ox < 4; ++ox) {
            float* base = out +
                ((((size_t)b * 32 + l31) * 64 + (x0 + ox)) * 64 + yy) * 64 +
                zh * 32 + hi * 4;
#pragma unroll
            for (int rq = 0; rq < 4; ++rq) {
                f32x4 v = { acc[oyi][ox][rq * 4 + 0], acc[oyi][ox][rq * 4 + 1],
                            acc[oyi][ox][rq * 4 + 2], acc[oyi][ox][rq * 4 + 3] };
                *reinterpret_cast<f32x4*>(base + rq * 8) = v;
            }
        }
    }
}

// ---------------------------------------------------------------------------
extern "C" void kernel_launch(void* const* d_in, const int* in_sizes, int n_in,
                              void* d_out, int out_size, void* d_ws, size_t ws_size,
                              hipStream_t stream) {
    const float* x      = (const float*)d_in[0];
    const float* weight = (const float*)d_in[1];
    const float* w_sc0  = (const float*)d_in[2];
    const float* w_sc1  = (const float*)d_in[3];
    float* out = (float*)d_out;

    char* ws = (char*)d_ws;
    unsigned short* xt  = (unsigned short*)ws;                 // 33,554,432 B
    unsigned short* kwb = (unsigned short*)(ws + 33554432);    //    256,000 B
    unsigned short* zpg = (unsigned short*)(ws + 33810432);    //      4,096 B

    (void)hipFuncSetAttribute((const void*)conv_mfma,
                              hipFuncAttributeMaxDynamicSharedMemorySize,
                              155648);

    hipLaunchKernelGGL(build_pack, dim3(NTAP), dim3(128), 0, stream,
                       weight, w_sc0, w_sc1, kwb);
    hipLaunchKernelGGL(xpose, dim3(64, 64, 2), dim3(256), 0, stream, x, xt);
    hipLaunchKernelGGL(zero_fill, dim3(1), dim3(256), 0, stream, (float4*)zpg);
    hipLaunchKernelGGL(conv_mfma, dim3(16, 8, 2), dim3(512), 155648, stream,
                       xt, kwb, zpg, out);
}

// Round 8
// 147.144 us; speedup vs baseline: 1.0238x; 1.0238x over previous
//
#include <hip/hip_runtime.h>
#include <math.h>

typedef __attribute__((ext_vector_type(8))) short short8;
typedef __attribute__((ext_vector_type(4))) float f32x4;
typedef __attribute__((ext_vector_type(16))) float f32x16;

#define NTAP 125
#define DCH 32

static __device__ __forceinline__ unsigned short f2bf(float f) {
    union { float f; unsigned u; } v; v.f = f;
    unsigned u = v.u;
    return (unsigned short)((u + 0x7FFFu + ((u >> 16) & 1u)) >> 16);
}

static __device__ __forceinline__ void gld_lds16(const void* g, void* l) {
    __builtin_amdgcn_global_load_lds(
        (const __attribute__((address_space(1))) unsigned int*)g,
        (__attribute__((address_space(3))) unsigned int*)l, 16, 0, 0);
}

// ---------------------------------------------------------------------------
// Kernel 1 (fused build+pack): build conv weights for tap t in LDS, then
// pack to bf16 B-fragments kwb[tap][kh][lane][8] for mfma_f32_32x32x16_bf16.
// Skip connection folded into center tap 62. (math verified R0-R7)
// ---------------------------------------------------------------------------
__global__ __launch_bounds__(128) void build_pack(
    const float* __restrict__ weight,
    const float* __restrict__ w_sc0,
    const float* __restrict__ w_sc1,
    unsigned short* __restrict__ kwb)
{
    const int t = blockIdx.x;
    const int dx = t / 25, dy = (t / 5) % 5, dz = t % 5;
    const float px = dx - 2.0f, py = dy - 2.0f, pz = dz - 2.0f;
    const float d = sqrtf(px * px + py * py + pz * pz);

    const float stepv = 2.5f / 6.0f;
    const float embc = 1.14136f * expf(2.0f);
    float emb[5];
#pragma unroll
    for (int n = 0; n < 5; ++n) {
        float diff = (d - stepv * (float)(n + 1)) / stepv;
        float a = diff + 1.0f, bb = 1.0f - diff;
        float v = 0.0f;
        if (a > 0.0f && bb > 0.0f)
            v = embc * expf(-1.0f / a) * expf(-1.0f / bb);
        emb[n] = v;
    }

    const float inv_d = (d > 0.0f) ? 1.0f / d : 0.0f;
    const float ux = px * inv_d, uy = py * inv_d, uz = pz * inv_d;
    const float s3 = 1.73205081f, s5 = 2.23606798f, s15 = 3.87298335f;
    float sh[9];
    sh[0] = 1.0f;
    sh[1] = s3 * ux; sh[2] = s3 * uy; sh[3] = s3 * uz;
    sh[4] = s15 * ux * uz;
    sh[5] = s15 * ux * uy;
    sh[6] = s5 * (uy * uy - 0.5f * (ux * ux + uz * uz));
    sh[7] = s15 * uy * uz;
    sh[8] = 0.5f * s15 * (uz * uz - ux * ux);

    const float i_s2 = 0.70710678f, i_s6 = 0.40824829f, i_s5 = 0.44721360f;
    float T[3][3];
    T[0][0] = i_s5 * (-sh[6] * i_s6 - sh[8] * i_s2);
    T[0][1] = i_s5 * (sh[5] * i_s2);
    T[0][2] = i_s5 * (sh[4] * i_s2);
    T[1][0] = T[0][1];
    T[1][1] = i_s5 * (2.0f * sh[6] * i_s6);
    T[1][2] = i_s5 * (sh[7] * i_s2);
    T[2][0] = T[0][2];
    T[2][1] = T[1][2];
    T[2][2] = i_s5 * (-sh[6] * i_s6 + sh[8] * i_s2);

    __shared__ float Wt[320];
    __shared__ float kws[1024];              // [ci=32][co=32] for this tap
    for (int col = threadIdx.x; col < 320; col += 128) {
        float a = 0.0f;
#pragma unroll
        for (int n = 0; n < 5; ++n) a += emb[n] * weight[n * 320 + col];
        Wt[col] = a * (1.0f / 125.0f);
    }
    __syncthreads();

    const float pw0 = 0.25f;
    const float pw1 = 0.35355339f;
    const float inv_s3 = 0.57735027f;
    const float inv_s8 = 0.35355339f;

    for (int idx = threadIdx.x; idx < 1024; idx += 128) {
        const int o = idx >> 5, i = idx & 31;
        float val;
        if (o < 8) {
            if (i < 8) {
                val = pw0 * Wt[i * 8 + o];
            } else {
                const int u = (i - 8) / 3, m = (i - 8) % 3;
                val = pw0 * inv_s3 * Wt[192 + u * 8 + o] * sh[1 + m];
            }
        } else {
            const int v = (o - 8) / 3, k = (o - 8) % 3;
            if (i < 8) {
                val = pw1 * inv_s3 * Wt[64 + i * 8 + v] * sh[1 + k];
            } else {
                const int u = (i - 8) / 3, m = (i - 8) % 3;
                float tv = Wt[256 + u * 8 + v] * T[m][k];
                if (m == k) tv += inv_s3 * Wt[128 + u * 8 + v];
                val = pw1 * tv;
            }
        }
        if (t == 62) {
            if (o < 8 && i < 8) {
                val += inv_s8 * w_sc0[i * 8 + o];
            } else if (o >= 8 && i >= 8) {
                const int u = (i - 8) / 3, m = (i - 8) % 3;
                const int v = (o - 8) / 3, k = (o - 8) % 3;
                if (m == k) val += inv_s8 * w_sc1[u * 8 + v];
            }
        }
        kws[i * 32 + o] = val;
    }
    __syncthreads();

    // pack: kwb[tap][kh][lane][8], ci = kh*16 + (l>>5)*8 + j, co = l&31
    const int tid = threadIdx.x;
    const int kh = tid >> 6, l = tid & 63;
    const int co = l & 31;
    const int cib = kh * 16 + (l >> 5) * 8;
    unsigned short v[8];
#pragma unroll
    for (int j = 0; j < 8; ++j)
        v[j] = f2bf(kws[(cib + j) * 32 + co]);
    uint4 o;
    o.x = (unsigned)v[0] | ((unsigned)v[1] << 16);
    o.y = (unsigned)v[2] | ((unsigned)v[3] << 16);
    o.z = (unsigned)v[4] | ((unsigned)v[5] << 16);
    o.w = (unsigned)v[6] | ((unsigned)v[7] << 16);
    *reinterpret_cast<uint4*>(kwb + ((size_t)(t * 2 + kh) * 64 + l) * 8) = o;
}

// ---------------------------------------------------------------------------
// Kernel 2: transpose x fp32 [b][ci][X][Y][Z] -> bf16 x_t[b][X][Y][Z][ci=32]
// ---------------------------------------------------------------------------
__global__ __launch_bounds__(256) void xpose(
    const float* __restrict__ x, unsigned short* __restrict__ xt)
{
    const int xx = blockIdx.x, yy = blockIdx.y, b = blockIdx.z;
    const int t = threadIdx.x;
    const int z = t & 63, part = t >> 6;
    const float* src = x + ((((size_t)b * 32) * 64 + xx) * 64 + yy) * 64 + z;
    unsigned short v[8];
#pragma unroll
    for (int j = 0; j < 8; ++j)
        v[j] = f2bf(src[(size_t)(part * 8 + j) * 262144]);
    uint4 o;
    o.x = (unsigned)v[0] | ((unsigned)v[1] << 16);
    o.y = (unsigned)v[2] | ((unsigned)v[3] << 16);
    o.z = (unsigned)v[4] | ((unsigned)v[5] << 16);
    o.w = (unsigned)v[6] | ((unsigned)v[7] << 16);
    *reinterpret_cast<uint4*>(
        xt + ((((size_t)b * 64 + xx) * 64 + yy) * 64 + z) * 32 + part * 8) = o;
}

__global__ void zero_fill(float4* p) {
    p[threadIdx.x] = make_float4(0.f, 0.f, 0.f, 0.f);
}

// ---------------------------------------------------------------------------
// Kernel 3: implicit-GEMM conv via mfma_f32_32x32x16_bf16.
// R8: 4-oy waves. R0-R7 showed schedule/read-count/occupancy all null at
// ~7800 cyc/step; the structural limiter is LDS-read:MFMA cycle ratio 1.34
// (m201's 62%-util GEMM runs at 0.94). Fix: block 256 thr / 4 waves,
// wave (zh,oyq) owns 4 oy x 4 ox -> acc[4][4] (256 acc regs, 1 wave/SIMD).
// B-fragment reads amortize over 4 oy (B/MFMA 0.5 -> 0.25); A-reads for
// the 4 oy share ONE address via asm offset:{0,4352,8704,13056}. Per-CU
// per-step reads 360 -> 260; LDS demand ~3500-4200 cyc < old step 7830.
// Latency hiding at 1 wave/SIMD via the R7-proven 2-deep asm ds_read
// pipeline (counted lgkmcnt, sched_barrier(0) after waits, rule #18).
// Skeleton = R6 (passing): tbuf slab, counted end-of-step vmcnt (never 0
// in main loop), raw s_barrier. Counts re-derived for 256 thr: slab = 9|8
// loads/wave (tid<128|else), Bs = 13|12 at dy-boundaries -> vmcnt(9|8)
// retires everything older than the newest slab issue.
// Grid 16*8*2 = 256 = 1 block/CU. LDS 155648 B: Bs 51200 + 3 x 34816.
// ---------------------------------------------------------------------------
__global__ __launch_bounds__(256, 1) void conv_mfma(
    const unsigned short* __restrict__ xt,   // [b][64][64][64][32] bf16
    const unsigned short* __restrict__ kwb,  // [125][2][64][8]
    const unsigned short* __restrict__ zpage,
    float* __restrict__ out)                 // [b][32][64][64][64]
{
    extern __shared__ unsigned short smem[];
    char* lds = (char*)smem;
    const unsigned lds0 = (unsigned)__builtin_amdgcn_groupstaticsize();

    const int tid = threadIdx.x;
    const int lane = tid & 63;
    const int wv = tid >> 6;                 // 0..3
    const int oyq = wv >> 1, zh = wv & 1;    // oy quad 0..1, z half
    const int x0 = blockIdx.x * 4, y0 = blockIdx.y * 8;
    const int b = blockIdx.z;
    const int l31 = lane & 31, hi = lane >> 5;

    // A-read LDS byte addr (buf0, oyi=0); oyi: +4352*oyi (asm offset imm);
    // buffers: + runtime rd in {0,34816,69632}.
    int abase[5][2];
#pragma unroll
    for (int dz = 0; dz < 5; ++dz) {
        const int s = zh * 32 + l31 + dz;
#pragma unroll
        for (int kh = 0; kh < 2; ++kh) {
            const int cph = (kh * 2 + hi) ^ ((s >> 1) & 3);
            abase[dz][kh] = (int)lds0 +
                51200 + ((((oyq * 4 * 68 + s) << 2) | cph) << 4);
        }
    }
    const unsigned baddr = lds0 + (unsigned)(lane * 16);  // Bs at offset 0

    // slab staging precompute: 2176 chunks, c = tid + p*256
    // (p<8 all threads; p==8 only tid<128 i.e. waves 0-1)
    int srow[9]; int soff[9]; bool szok[9];
#pragma unroll
    for (int p = 0; p < 9; ++p) {
        const int c = tid + p * 256;
        const int row = c / 272;
        const int rem = c - row * 272;
        const int slot = rem >> 2;
        const int clog = (rem & 3) ^ ((slot >> 1) & 3);
        const int z = slot - 2;
        srow[p] = row;
        szok[p] = ((unsigned)z < 64u);
        soff[p] = row * 2048 + z * 32 + clog * 8;
    }

    // Bs staging precompute: 3200 chunks, c = tid + k*256
    // (k<12 all threads; k==12 only tid<128)
    int bsrc[13];
#pragma unroll
    for (int k = 0; k < 13; ++k) {
        const int c = tid + k * 256;
        const int tp = c >> 7, rem = c & 127;
        const int dxx = tp / 5, dzz = tp - dxx * 5;
        bsrc[k] = (dxx * 25 + dzz) * 128 + rem;
    }

    auto issue_bs = [&](int dy) {
#pragma unroll
        for (int k = 0; k < 12; ++k) {
            gld_lds16(kwb + ((size_t)(bsrc[k] + dy * 640)) * 8,
                      lds + (wv * 64 + k * 256) * 16);
        }
        if (wv < 2) {
            gld_lds16(kwb + ((size_t)(bsrc[12] + dy * 640)) * 8,
                      lds + (wv * 64 + 3072) * 16);
        }
    };

    auto issue_slab = [&](int dyn, int xln, int dstoff) {
        const int yyb = y0 + dyn - 2;
        const int xx = x0 + xln - 2;
        const bool xok = ((unsigned)xx < 64u);
        const long long xyb =
            (long long)(b * 64 + xx) * 131072 + (long long)yyb * 2048;
        char* dst = lds + 51200 + dstoff;    // dstoff uniform
#pragma unroll
        for (int p = 0; p < 8; ++p) {
            const int yy = yyb + srow[p];
            const bool ok = xok && ((unsigned)yy < 64u) && szok[p];
            const unsigned short* src = ok ? (xt + xyb + soff[p]) : zpage;
            gld_lds16(src, dst + (wv * 64 + p * 256) * 16);
        }
        if (wv < 2) {   // chunks 2048..2175
            const int yy = yyb + srow[8];
            const bool ok = xok && ((unsigned)yy < 64u) && szok[8];
            const unsigned short* src = ok ? (xt + xyb + soff[8]) : zpage;
            gld_lds16(src, dst + (wv * 64 + 2048) * 16);
        }
    };

    // counted wait: retire everything older than my newest slab issue
    auto wait_keep_slab = [&]() {
        if (wv < 2) asm volatile("s_waitcnt vmcnt(9)" ::: "memory");
        else        asm volatile("s_waitcnt vmcnt(8)" ::: "memory");
    };

    f32x16 acc[4][4];
#pragma unroll
    for (int oyi = 0; oyi < 4; ++oyi)
#pragma unroll
        for (int ox = 0; ox < 4; ++ox)
#pragma unroll
            for (int e = 0; e < 16; ++e) acc[oyi][ox][e] = 0.0f;

    // prologue: Bs(0), slab(0,0)->buf0, slab(0,1)->buf1; retire Bs+slab0,
    // keep slab1 in flight.
    issue_bs(0);
    __builtin_amdgcn_sched_barrier(0);
    issue_slab(0, 0, 0);
    __builtin_amdgcn_sched_barrier(0);
    issue_slab(0, 1, 34816);
    __builtin_amdgcn_sched_barrier(0);
    wait_keep_slab();
    __builtin_amdgcn_s_barrier();

    int rd = 0;            // buffer being computed this step
    int prev = 69632;      // buffer read last step = stage target for t+2

    for (int dy = 0; dy < 5; ++dy) {
#pragma unroll
        for (int xl = 0; xl < 8; ++xl) {
            const bool bdry = (xl == 0) && (dy > 0);
            if (bdry) {
                issue_bs(dy);
                __builtin_amdgcn_sched_barrier(0);
            }
            // stage slab(t+2) into the buffer read at t-1
            if (!(dy == 4 && xl >= 6)) {
                const int ndy = (xl >= 6) ? dy + 1 : dy;
                const int nxl = (xl >= 6) ? xl - 6 : xl + 2;
                issue_slab(ndy, nxl, prev);
                __builtin_amdgcn_sched_barrier(0);
            }
            if (bdry) {
                // retire slab(t+1)+Bs(dy), keep slab(t+2) in flight
                wait_keep_slab();
                __builtin_amdgcn_s_barrier();
            }

            // ---- compute from buf at rd: 2-deep asm ds_read pipeline ----
            const int oxlo = (xl - 4 > 0) ? (xl - 4) : 0;
            const int oxhi = (xl < 3) ? xl : 3;
            const int S = 4 + (oxhi - oxlo + 1);     // reads per group: 5..8

            short8 A[2][4], B[2][4];

            // issue group 0 (dz=0, kh=0): one addr, 4 oy via offset imms
            {
                const unsigned aa = (unsigned)(abase[0][0] + rd);
                asm volatile("ds_read_b128 %0, %1"
                             : "=&v"(A[0][0]) : "v"(aa));
                asm volatile("ds_read_b128 %0, %1 offset:4352"
                             : "=&v"(A[0][1]) : "v"(aa));
                asm volatile("ds_read_b128 %0, %1 offset:8704"
                             : "=&v"(A[0][2]) : "v"(aa));
                asm volatile("ds_read_b128 %0, %1 offset:13056"
                             : "=&v"(A[0][3]) : "v"(aa));
#pragma unroll
                for (int ox = 0; ox < 4; ++ox) {
                    if (ox < oxlo || ox > oxhi) continue;
                    const unsigned bb = baddr +
                        (unsigned)((((xl - ox) * 5 + 0) * 2 + 0) << 10);
                    asm volatile("ds_read_b128 %0, %1"
                                 : "=&v"(B[0][ox]) : "v"(bb));
                }
            }
#pragma unroll
            for (int g = 0; g < 10; ++g) {
                const int cs = g & 1;
                if (g < 9) {
                    const int g1 = g + 1;
                    const int dz1 = g1 >> 1, kh1 = g1 & 1, ns = g1 & 1;
                    const unsigned aa = (unsigned)(abase[dz1][kh1] + rd);
                    asm volatile("ds_read_b128 %0, %1"
                                 : "=&v"(A[ns][0]) : "v"(aa));
                    asm volatile("ds_read_b128 %0, %1 offset:4352"
                                 : "=&v"(A[ns][1]) : "v"(aa));
                    asm volatile("ds_read_b128 %0, %1 offset:8704"
                                 : "=&v"(A[ns][2]) : "v"(aa));
                    asm volatile("ds_read_b128 %0, %1 offset:13056"
                                 : "=&v"(A[ns][3]) : "v"(aa));
#pragma unroll
                    for (int ox = 0; ox < 4; ++ox) {
                        if (ox < oxlo || ox > oxhi) continue;
                        const unsigned bb = baddr +
                            (unsigned)((((xl - ox) * 5 + dz1) * 2 + kh1)
                                       << 10);
                        asm volatile("ds_read_b128 %0, %1"
                                     : "=&v"(B[ns][ox]) : "v"(bb));
                    }
                    // wait until only group g+1's S reads are outstanding
                    if (S == 5)
                        asm volatile("s_waitcnt lgkmcnt(5)" ::: "memory");
                    else if (S == 6)
                        asm volatile("s_waitcnt lgkmcnt(6)" ::: "memory");
                    else if (S == 7)
                        asm volatile("s_waitcnt lgkmcnt(7)" ::: "memory");
                    else
                        asm volatile("s_waitcnt lgkmcnt(8)" ::: "memory");
                } else {
                    asm volatile("s_waitcnt lgkmcnt(0)" ::: "memory");
                }
                __builtin_amdgcn_sched_barrier(0);   // rule #18
#pragma unroll
                for (int ox = 0; ox < 4; ++ox) {
                    if (ox < oxlo || ox > oxhi) continue;
#pragma unroll
                    for (int oyi = 0; oyi < 4; ++oyi) {
                        acc[oyi][ox] = __builtin_amdgcn_mfma_f32_32x32x16_bf16(
                            A[cs][oyi], B[cs][ox], acc[oyi][ox], 0, 0, 0);
                    }
                }
            }

            // end of step: retire slab(t+1), keep slab(t+2) in flight
            if (dy == 4 && xl >= 6) {
                asm volatile("s_waitcnt vmcnt(0)" ::: "memory");
            } else {
                wait_keep_slab();
            }
            if (!(dy == 4 && xl == 7))
                __builtin_amdgcn_s_barrier();

            // rotate buffers
            const int tmp = rd;
            rd = (rd == 69632) ? 0 : rd + 34816;
            prev = tmp;
        }
    }

    // epilogue: D lane l: co = l&31, z = zh*32 + rq*8 + (l>>5)*4 + (r&3)
#pragma unroll
    for (int oyi = 0; oyi < 4; ++oyi) {
        const int yy = y0 + oyq * 4 + oyi;
#pragma unroll
        for (int ox = 0; ox < 4; ++ox) {
            float* base = out +
                ((((size_t)b * 32 + l31) * 64 + (x0 + ox)) * 64 + yy) * 64 +
                zh * 32 + hi * 4;
#pragma unroll
            for (int rq = 0; rq < 4; ++rq) {
                f32x4 v = { acc[oyi][ox][rq * 4 + 0], acc[oyi][ox][rq * 4 + 1],
                            acc[oyi][ox][rq * 4 + 2], acc[oyi][ox][rq * 4 + 3] };
                *reinterpret_cast<f32x4*>(base + rq * 8) = v;
            }
        }
    }
}

// ---------------------------------------------------------------------------
extern "C" void kernel_launch(void* const* d_in, const int* in_sizes, int n_in,
                              void* d_out, int out_size, void* d_ws, size_t ws_size,
                              hipStream_t stream) {
    const float* x      = (const float*)d_in[0];
    const float* weight = (const float*)d_in[1];
    const float* w_sc0  = (const float*)d_in[2];
    const float* w_sc1  = (const float*)d_in[3];
    float* out = (float*)d_out;

    char* ws = (char*)d_ws;
    unsigned short* xt  = (unsigned short*)ws;                 // 33,554,432 B
    unsigned short* kwb = (unsigned short*)(ws + 33554432);    //    256,000 B
    unsigned short* zpg = (unsigned short*)(ws + 33810432);    //      4,096 B

    (void)hipFuncSetAttribute((const void*)conv_mfma,
                              hipFuncAttributeMaxDynamicSharedMemorySize,
                              155648);

    hipLaunchKernelGGL(build_pack, dim3(NTAP), dim3(128), 0, stream,
                       weight, w_sc0, w_sc1, kwb);
    hipLaunchKernelGGL(xpose, dim3(64, 64, 2), dim3(256), 0, stream, x, xt);
    hipLaunchKernelGGL(zero_fill, dim3(1), dim3(256), 0, stream, (float4*)zpg);
    hipLaunchKernelGGL(conv_mfma, dim3(16, 8, 2), dim3(256), 155648, stream,
                       xt, kwb, zpg, out);
}

// Round 9
// 145.742 us; speedup vs baseline: 1.0336x; 1.0096x over previous
//
#include <hip/hip_runtime.h>
#include <math.h>

typedef __attribute__((ext_vector_type(8))) short short8;
typedef __attribute__((ext_vector_type(4))) float f32x4;
typedef __attribute__((ext_vector_type(16))) float f32x16;

#define NTAP 125
#define DCH 32

static __device__ __forceinline__ unsigned short f2bf(float f) {
    union { float f; unsigned u; } v; v.f = f;
    unsigned u = v.u;
    return (unsigned short)((u + 0x7FFFu + ((u >> 16) & 1u)) >> 16);
}

static __device__ __forceinline__ void gld_lds16(const void* g, void* l) {
    __builtin_amdgcn_global_load_lds(
        (const __attribute__((address_space(1))) unsigned int*)g,
        (__attribute__((address_space(3))) unsigned int*)l, 16, 0, 0);
}

// ---------------------------------------------------------------------------
// Kernel 1 (fused build+pack): build conv weights for tap t in LDS, then
// pack to bf16 B-fragments kwb[tap][kh][lane][8] for mfma_f32_32x32x16_bf16.
// Skip connection folded into center tap 62. (math verified R0-R8)
// ---------------------------------------------------------------------------
__global__ __launch_bounds__(128) void build_pack(
    const float* __restrict__ weight,
    const float* __restrict__ w_sc0,
    const float* __restrict__ w_sc1,
    unsigned short* __restrict__ kwb)
{
    const int t = blockIdx.x;
    const int dx = t / 25, dy = (t / 5) % 5, dz = t % 5;
    const float px = dx - 2.0f, py = dy - 2.0f, pz = dz - 2.0f;
    const float d = sqrtf(px * px + py * py + pz * pz);

    const float stepv = 2.5f / 6.0f;
    const float embc = 1.14136f * expf(2.0f);
    float emb[5];
#pragma unroll
    for (int n = 0; n < 5; ++n) {
        float diff = (d - stepv * (float)(n + 1)) / stepv;
        float a = diff + 1.0f, bb = 1.0f - diff;
        float v = 0.0f;
        if (a > 0.0f && bb > 0.0f)
            v = embc * expf(-1.0f / a) * expf(-1.0f / bb);
        emb[n] = v;
    }

    const float inv_d = (d > 0.0f) ? 1.0f / d : 0.0f;
    const float ux = px * inv_d, uy = py * inv_d, uz = pz * inv_d;
    const float s3 = 1.73205081f, s5 = 2.23606798f, s15 = 3.87298335f;
    float sh[9];
    sh[0] = 1.0f;
    sh[1] = s3 * ux; sh[2] = s3 * uy; sh[3] = s3 * uz;
    sh[4] = s15 * ux * uz;
    sh[5] = s15 * ux * uy;
    sh[6] = s5 * (uy * uy - 0.5f * (ux * ux + uz * uz));
    sh[7] = s15 * uy * uz;
    sh[8] = 0.5f * s15 * (uz * uz - ux * ux);

    const float i_s2 = 0.70710678f, i_s6 = 0.40824829f, i_s5 = 0.44721360f;
    float T[3][3];
    T[0][0] = i_s5 * (-sh[6] * i_s6 - sh[8] * i_s2);
    T[0][1] = i_s5 * (sh[5] * i_s2);
    T[0][2] = i_s5 * (sh[4] * i_s2);
    T[1][0] = T[0][1];
    T[1][1] = i_s5 * (2.0f * sh[6] * i_s6);
    T[1][2] = i_s5 * (sh[7] * i_s2);
    T[2][0] = T[0][2];
    T[2][1] = T[1][2];
    T[2][2] = i_s5 * (-sh[6] * i_s6 + sh[8] * i_s2);

    __shared__ float Wt[320];
    __shared__ float kws[1024];              // [ci=32][co=32] for this tap
    for (int col = threadIdx.x; col < 320; col += 128) {
        float a = 0.0f;
#pragma unroll
        for (int n = 0; n < 5; ++n) a += emb[n] * weight[n * 320 + col];
        Wt[col] = a * (1.0f / 125.0f);
    }
    __syncthreads();

    const float pw0 = 0.25f;
    const float pw1 = 0.35355339f;
    const float inv_s3 = 0.57735027f;
    const float inv_s8 = 0.35355339f;

    for (int idx = threadIdx.x; idx < 1024; idx += 128) {
        const int o = idx >> 5, i = idx & 31;
        float val;
        if (o < 8) {
            if (i < 8) {
                val = pw0 * Wt[i * 8 + o];
            } else {
                const int u = (i - 8) / 3, m = (i - 8) % 3;
                val = pw0 * inv_s3 * Wt[192 + u * 8 + o] * sh[1 + m];
            }
        } else {
            const int v = (o - 8) / 3, k = (o - 8) % 3;
            if (i < 8) {
                val = pw1 * inv_s3 * Wt[64 + i * 8 + v] * sh[1 + k];
            } else {
                const int u = (i - 8) / 3, m = (i - 8) % 3;
                float tv = Wt[256 + u * 8 + v] * T[m][k];
                if (m == k) tv += inv_s3 * Wt[128 + u * 8 + v];
                val = pw1 * tv;
            }
        }
        if (t == 62) {
            if (o < 8 && i < 8) {
                val += inv_s8 * w_sc0[i * 8 + o];
            } else if (o >= 8 && i >= 8) {
                const int u = (i - 8) / 3, m = (i - 8) % 3;
                const int v = (o - 8) / 3, k = (o - 8) % 3;
                if (m == k) val += inv_s8 * w_sc1[u * 8 + v];
            }
        }
        kws[i * 32 + o] = val;
    }
    __syncthreads();

    // pack: kwb[tap][kh][lane][8], ci = kh*16 + (l>>5)*8 + j, co = l&31
    const int tid = threadIdx.x;
    const int kh = tid >> 6, l = tid & 63;
    const int co = l & 31;
    const int cib = kh * 16 + (l >> 5) * 8;
    unsigned short v[8];
#pragma unroll
    for (int j = 0; j < 8; ++j)
        v[j] = f2bf(kws[(cib + j) * 32 + co]);
    uint4 o;
    o.x = (unsigned)v[0] | ((unsigned)v[1] << 16);
    o.y = (unsigned)v[2] | ((unsigned)v[3] << 16);
    o.z = (unsigned)v[4] | ((unsigned)v[5] << 16);
    o.w = (unsigned)v[6] | ((unsigned)v[7] << 16);
    *reinterpret_cast<uint4*>(kwb + ((size_t)(t * 2 + kh) * 64 + l) * 8) = o;
}

// ---------------------------------------------------------------------------
// Kernel 2: transpose x fp32 [b][ci][X][Y][Z] -> bf16 x_t[b][X][Y][Z][ci=32]
// ---------------------------------------------------------------------------
__global__ __launch_bounds__(256) void xpose(
    const float* __restrict__ x, unsigned short* __restrict__ xt)
{
    const int xx = blockIdx.x, yy = blockIdx.y, b = blockIdx.z;
    const int t = threadIdx.x;
    const int z = t & 63, part = t >> 6;
    const float* src = x + ((((size_t)b * 32) * 64 + xx) * 64 + yy) * 64 + z;
    unsigned short v[8];
#pragma unroll
    for (int j = 0; j < 8; ++j)
        v[j] = f2bf(src[(size_t)(part * 8 + j) * 262144]);
    uint4 o;
    o.x = (unsigned)v[0] | ((unsigned)v[1] << 16);
    o.y = (unsigned)v[2] | ((unsigned)v[3] << 16);
    o.z = (unsigned)v[4] | ((unsigned)v[5] << 16);
    o.w = (unsigned)v[6] | ((unsigned)v[7] << 16);
    *reinterpret_cast<uint4*>(
        xt + ((((size_t)b * 64 + xx) * 64 + yy) * 64 + z) * 32 + part * 8) = o;
}

__global__ void zero_fill(float4* p) {
    p[threadIdx.x] = make_float4(0.f, 0.f, 0.f, 0.f);
}

// ---------------------------------------------------------------------------
// Kernel 3: implicit-GEMM conv via mfma_f32_32x32x16_bf16.
// R9 = R3 base (best passing conv, 126 us: dbuf slab, gld_lds staging,
// __syncthreads 2-phase) + two levers against wave-lockstep:
// R8's arithmetic showed two waves on a SIMD SUM their timelines (step =
// 2 x single-wave time): identical code -> identical wait points -> reads
// queue behind each other and MFMA/LDS phases alternate instead of
// overlapping.
// (1) PHASE STAGGER: waves 4-7 run the 10 (dz,kh) groups rotated by 5.
//     SIMD pairs are (wv, wv+4) -> each SIMD holds one wave of each order,
//     so one wave's MFMA cluster coincides with the other's read cluster.
//     Legal: groups are K-slices accumulating into the same acc (fp32
//     order change only). All indices compile-time (macro, rule #20).
// (2) T5 setprio(1)/(0) around each group's MFMA cluster (m218b regime:
//     phase-diverse waves; null only in lockstep m190 - which we were).
// Block 512 thr (8 waves), tile 4x*8y*64z, grid 16*8*2 = 256 = 1 block/CU.
// LDS 120832 B: Bs[25][2][64][16B] (51200) + slab dbuf 2 x 34816.
// ---------------------------------------------------------------------------
__global__ __launch_bounds__(512, 2) void conv_mfma(
    const unsigned short* __restrict__ xt,   // [b][64][64][64][32] bf16
    const unsigned short* __restrict__ kwb,  // [125][2][64][8]
    const unsigned short* __restrict__ zpage,
    float* __restrict__ out)                 // [b][32][64][64][64]
{
    extern __shared__ unsigned short smem[];
    char* lds = (char*)smem;

    const int tid = threadIdx.x;
    const int lane = tid & 63;
    const int wv = tid >> 6;                 // 0..7
    const int oyp = wv >> 1, zh = wv & 1;    // oy pair 0..3, z half
    const int x0 = blockIdx.x * 4, y0 = blockIdx.y * 8;
    const int b = blockIdx.z;
    const int l31 = lane & 31, hi = lane >> 5;
    const bool stag = (wv >= 4);             // SIMD pairs are (wv, wv+4)

    // A-read base (slab buf0, oyi=0); oyi=1: +4352, buf1: +34816 (imm-folded)
    int abase[5][2];
#pragma unroll
    for (int dz = 0; dz < 5; ++dz) {
        const int s = zh * 32 + l31 + dz;
#pragma unroll
        for (int kh = 0; kh < 2; ++kh) {
            const int cph = (kh * 2 + hi) ^ ((s >> 1) & 3);
            abase[dz][kh] =
                51200 + ((((oyp * 2 * 68 + s) << 2) | cph) << 4);
        }
    }
    const int bbase = lane * 16;

    // slab staging precompute: 2176 chunks, c = tid + p*512
    // (p<4 all threads; p==4 only waves 0-1)
    int srow[5]; int soff[5]; bool szok[5];
#pragma unroll
    for (int p = 0; p < 5; ++p) {
        const int c = tid + p * 512;
        const int row = c / 272;
        const int rem = c - row * 272;
        const int slot = rem >> 2;
        const int clog = (rem & 3) ^ ((slot >> 1) & 3);
        const int z = slot - 2;
        srow[p] = row;
        szok[p] = ((unsigned)z < 64u);
        soff[p] = row * 2048 + z * 32 + clog * 8;
    }

    // Bs staging precompute: 3200 chunks, c = tid + k*512
    int bsrc[7];
#pragma unroll
    for (int k = 0; k < 7; ++k) {
        const int c = tid + k * 512;
        const int tp = c >> 7, rem = c & 127;
        const int dxx = tp / 5, dzz = tp - dxx * 5;
        bsrc[k] = (dxx * 25 + dzz) * 128 + rem;
    }

    auto issue_bs = [&](int dy) {
#pragma unroll
        for (int k = 0; k < 7; ++k) {
            const int c0 = wv * 64 + k * 512;   // wave-uniform dest base
            if (c0 < 3200) {
                gld_lds16(kwb + ((size_t)(bsrc[k] + dy * 640)) * 8,
                          lds + c0 * 16);
            }
        }
    };

    auto issue_slab = [&](int dyn, int xln, int bufi) {
        const int yyb = y0 + dyn - 2;
        const int xx = x0 + xln - 2;
        const bool xok = ((unsigned)xx < 64u);
        const long long xyb =
            (long long)(b * 64 + xx) * 131072 + (long long)yyb * 2048;
        char* dst = lds + 51200 + bufi * 34816;
#pragma unroll
        for (int p = 0; p < 4; ++p) {
            const int yy = yyb + srow[p];
            const bool ok = xok && ((unsigned)yy < 64u) && szok[p];
            const unsigned short* src = ok ? (xt + xyb + soff[p]) : zpage;
            gld_lds16(src, dst + (wv * 64 + p * 512) * 16);
        }
        if (wv < 2) {   // chunks 2048..2175
            const int yy = yyb + srow[4];
            const bool ok = xok && ((unsigned)yy < 64u) && szok[4];
            const unsigned short* src = ok ? (xt + xyb + soff[4]) : zpage;
            gld_lds16(src, dst + (wv * 64 + 2048) * 16);
        }
    };

    f32x16 acc[2][4];
#pragma unroll
    for (int oyi = 0; oyi < 2; ++oyi)
#pragma unroll
        for (int ox = 0; ox < 4; ++ox)
#pragma unroll
            for (int e = 0; e < 16; ++e) acc[oyi][ox][e] = 0.0f;

    // prologue: Bs(0) + slab(0,0) -> buf0, full drain
    issue_bs(0);
    issue_slab(0, 0, 0);
    __syncthreads();

// one (dz,kh) group: 2 A-reads (oy pair), MFMA cluster wrapped in setprio
#define GROUP(DZ, KH)                                                        \
    {                                                                        \
        const char* ap_ = lds + abase[DZ][KH] + boff;                        \
        const short8 a0_ = *reinterpret_cast<const short8*>(ap_);            \
        const short8 a1_ = *reinterpret_cast<const short8*>(ap_ + 4352);     \
        __builtin_amdgcn_s_setprio(1);                                       \
        _Pragma("unroll")                                                    \
        for (int ox = 0; ox < 4; ++ox) {                                     \
            const int dxv = xl - ox;                                         \
            if (dxv < 0 || dxv > 4) continue;                                \
            const short8 bf_ = *reinterpret_cast<const short8*>(             \
                lds + bbase + (((dxv * 5 + (DZ)) * 2 + (KH)) << 10));        \
            acc[0][ox] = __builtin_amdgcn_mfma_f32_32x32x16_bf16(            \
                a0_, bf_, acc[0][ox], 0, 0, 0);                              \
            acc[1][ox] = __builtin_amdgcn_mfma_f32_32x32x16_bf16(            \
                a1_, bf_, acc[1][ox], 0, 0, 0);                              \
        }                                                                    \
        __builtin_amdgcn_s_setprio(0);                                       \
    }

    for (int dy = 0; dy < 5; ++dy) {
#pragma unroll
        for (int xl = 0; xl < 8; ++xl) {
            if (xl == 0) {
                if (dy > 0) {
                    // restage Bs(dy) (prev readers done at last syncthreads)
                    issue_bs(dy);
                    __builtin_amdgcn_sched_barrier(0);
                    // prefetch slab(dy,1) -> buf1 (stays in flight)
                    issue_slab(dy, 1, 1);
                    __builtin_amdgcn_sched_barrier(0);
                    // counted wait: retire Bs, keep slab prefetch in flight
                    if (wv < 2)
                        asm volatile("s_waitcnt vmcnt(5)" ::: "memory");
                    else
                        asm volatile("s_waitcnt vmcnt(4)" ::: "memory");
                    __builtin_amdgcn_s_barrier();
                    __builtin_amdgcn_sched_barrier(0);
                } else {
                    // dy==0: Bs(0)+slab(0,0) visible from prologue barrier
                    issue_slab(0, 1, 1);
                }
            } else if (!(dy == 4 && xl == 7)) {
                // prefetch next step's slab into the other buffer
                issue_slab(xl == 7 ? dy + 1 : dy, xl == 7 ? 0 : xl + 1,
                           (xl & 1) ^ 1);
            }

            // compute from buf[xl&1] (boff is a compile-time immediate);
            // group order staggered by half a phase between SIMD-pair waves
            const int boff = (xl & 1) * 34816;
            if (stag) {
                GROUP(2, 1); GROUP(3, 0); GROUP(3, 1); GROUP(4, 0);
                GROUP(4, 1); GROUP(0, 0); GROUP(0, 1); GROUP(1, 0);
                GROUP(1, 1); GROUP(2, 0);
            } else {
                GROUP(0, 0); GROUP(0, 1); GROUP(1, 0); GROUP(1, 1);
                GROUP(2, 0); GROUP(2, 1); GROUP(3, 0); GROUP(3, 1);
                GROUP(4, 0); GROUP(4, 1);
            }

            // END barrier: drains this step's prefetch (hidden by compute)
            __syncthreads();
        }
    }
#undef GROUP

    // epilogue: D lane l: co = l&31, z = zh*32 + rq*8 + (l>>5)*4 + (r&3)
#pragma unroll
    for (int oyi = 0; oyi < 2; ++oyi) {
        const int yy = y0 + oyp * 2 + oyi;
#pragma unroll
        for (int ox = 0; ox < 4; ++ox) {
            float* base = out +
                ((((size_t)b * 32 + l31) * 64 + (x0 + ox)) * 64 + yy) * 64 +
                zh * 32 + hi * 4;
#pragma unroll
            for (int rq = 0; rq < 4; ++rq) {
                f32x4 v = { acc[oyi][ox][rq * 4 + 0], acc[oyi][ox][rq * 4 + 1],
                            acc[oyi][ox][rq * 4 + 2], acc[oyi][ox][rq * 4 + 3] };
                *reinterpret_cast<f32x4*>(base + rq * 8) = v;
            }
        }
    }
}

// ---------------------------------------------------------------------------
extern "C" void kernel_launch(void* const* d_in, const int* in_sizes, int n_in,
                              void* d_out, int out_size, void* d_ws, size_t ws_size,
                              hipStream_t stream) {
    const float* x      = (const float*)d_in[0];
    const float* weight = (const float*)d_in[1];
    const float* w_sc0  = (const float*)d_in[2];
    const float* w_sc1  = (const float*)d_in[3];
    float* out = (float*)d_out;

    char* ws = (char*)d_ws;
    unsigned short* xt  = (unsigned short*)ws;                 // 33,554,432 B
    unsigned short* kwb = (unsigned short*)(ws + 33554432);    //    256,000 B
    unsigned short* zpg = (unsigned short*)(ws + 33810432);    //      4,096 B

    (void)hipFuncSetAttribute((const void*)conv_mfma,
                              hipFuncAttributeMaxDynamicSharedMemorySize,
                              120832);

    hipLaunchKernelGGL(build_pack, dim3(NTAP), dim3(128), 0, stream,
                       weight, w_sc0, w_sc1, kwb);
    hipLaunchKernelGGL(xpose, dim3(64, 64, 2), dim3(256), 0, stream, x, xt);
    hipLaunchKernelGGL(zero_fill, dim3(1), dim3(256), 0, stream, (float4*)zpg);
    hipLaunchKernelGGL(conv_mfma, dim3(16, 8, 2), dim3(512), 120832, stream,
                       xt, kwb, zpg, out);
}